// Round 1
// baseline (184.662 us; speedup 1.0000x reference)
//
#include <hip/hip_runtime.h>

// Problem: T=2^21 sequential nonlinear storage recurrence + per-column z-score.
// Strategy: contractive recurrence (|ds'/ds| ~ 0.988/step) -> chunked scan with
// redundant warm-up. C=16384 chunks of L=128 outputs, each warmed up W=1024
// steps from s=0. One chunk per lane, 256 waves -> latency-bound serial chain.

#define T_TOTAL  (1 << 21)
#define L_CHUNK  128
#define W_WARM   1024
#define STEPS    (W_WARM + L_CHUNK)          // 1152, divisible by PF
#define C_CHUNKS (T_TOTAL / L_CHUNK)         // 16384
#define PF       16                          // prefetch distance / unroll

__device__ __forceinline__ float tanh_small(float x) {
    // tanh(x) for |x| <= ~0.03 : x - x^3/3 + 2x^5/15, poly error ~5e-12
    float x2 = x * x;
    return x * fmaf(x2, fmaf(x2, 0.13333334f, -0.33333334f), 1.0f);
}

__global__ __launch_bounds__(64) void scan_kernel(const float2* __restrict__ xp,
                                                  const float* __restrict__ x1p,
                                                  float* __restrict__ out,
                                                  double* __restrict__ stats) {
    const float x1s    = x1p[0];
    const float inv_x1 = 1.0f / x1s;
    const float c449   = (4.0f / 9.0f) * inv_x1;

    const int k = blockIdx.x * 64 + threadIdx.x;   // chunk id
    int t = k * L_CHUNK - W_WARM;

    float2 buf[PF];
#pragma unroll
    for (int j = 0; j < PF; ++j) {
        int tl = t + j;
        tl = tl < 0 ? 0 : tl;
        buf[j] = xp[tl];
    }

    float s = 0.0f;
    float sum0 = 0, sum1 = 0, sum2 = 0, sum3 = 0, sum4 = 0, sum5 = 0;
    float sq0 = 0, sq1 = 0, sq2 = 0, sq3 = 0, sq4 = 0, sq5 = 0;

    for (int i = 0; i < STEPS; i += PF) {
        const bool emit = (i >= W_WARM);   // W%PF==0 -> uniform per group
#pragma unroll
        for (int j = 0; j < PF; ++j) {
            float2 d = buf[j];
            // prefetch PF steps ahead (clamped; clamped loads are masked below)
            int tl = t + PF;
            tl = tl < 0 ? 0 : tl;
            tl = tl > (T_TOTAL - 1) ? (T_TOTAL - 1) : tl;
            buf[j] = xp[tl];

            float pn = fmaxf(d.x - d.y, 0.0f);
            float en = fmaxf(d.y - d.x, 0.0f);
            if (t < 0) { pn = 0.0f; en = 0.0f; }   // identity step while s==0

            // off-chain (depends only on t)
            float tp = tanh_small(pn * inv_x1);
            float te = tanh_small(en * inv_x1);

            // dependent chain on s
            float r   = s * inv_x1;
            float d1  = fmaf(r, tp, 1.0f);
            float rc1 = __builtin_amdgcn_rcpf(d1);
            float a   = fmaf(-r, r, 1.0f);
            float p_s = (x1s * tp) * (a * rc1);
            float d2  = fmaf(-te, r, 1.0f + te);
            float rc2 = __builtin_amdgcn_rcpf(d2);
            float e_s = (s * (2.0f - r)) * (te * rc2);
            float s1  = s + (p_s - e_s);
            float y   = s1 * c449;
            float y2  = y * y;
            float tq  = fmaf(y2, y2, 1.0f);
            float rs  = __builtin_amdgcn_rsqf(__builtin_amdgcn_sqrtf(tq)); // tq^-1/4
            float s2  = s1 * rs;
            float perc = s1 - s2;
            s = s2;

            if (emit) {
                out[6 * t + 4] = p_s;
                out[6 * t + 5] = perc;
                sum0 += d.x;  sq0 = fmaf(d.x, d.x, sq0);
                sum1 += d.y;  sq1 = fmaf(d.y, d.y, sq1);
                sum2 += pn;   sq2 = fmaf(pn, pn, sq2);
                sum3 += en;   sq3 = fmaf(en, en, sq3);
                sum4 += p_s;  sq4 = fmaf(p_s, p_s, sq4);
                sum5 += perc; sq5 = fmaf(perc, perc, sq5);
            }
            ++t;
        }
    }

    double v[12] = {sum0, sum1, sum2, sum3, sum4, sum5,
                    sq0, sq1, sq2, sq3, sq4, sq5};
#pragma unroll
    for (int c = 0; c < 12; ++c) {
        double val = v[c];
        for (int off = 32; off > 0; off >>= 1)
            val += __shfl_down(val, off, 64);
        if (threadIdx.x == 0) atomicAdd(&stats[c], val);
    }
}

__global__ void finalize_stats(const double* __restrict__ stats,
                               float* __restrict__ musig) {
    int c = threadIdx.x;
    if (c < 6) {
        double sum = stats[c], sumsq = stats[6 + c];
        double n = (double)T_TOTAL;
        double mu = sum / n;
        double var = (sumsq - sum * sum / n) / (n - 1.0);
        double sig = sqrt(var);
        musig[c] = (float)mu;
        musig[6 + c] = (float)(1.0 / sig);
    }
}

__global__ __launch_bounds__(256) void normalize_kernel(const float4* __restrict__ xp4,
                                                        float* __restrict__ out,
                                                        const float* __restrict__ musig) {
    float mu[6], is[6];
#pragma unroll
    for (int c = 0; c < 6; ++c) { mu[c] = musig[c]; is[c] = musig[6 + c]; }

    int idx = blockIdx.x * blockDim.x + threadIdx.x;
    int stride = gridDim.x * blockDim.x;
    for (int p = idx; p < T_TOTAL / 2; p += stride) {
        float4 xv = xp4[p];                         // rows 2p, 2p+1
        float* o = out + 12 * (size_t)p;
        float2 pp0 = *(const float2*)(o + 4);       // p_s, perc of row 2p
        float2 pp1 = *(const float2*)(o + 10);      // p_s, perc of row 2p+1
        float pn0 = fmaxf(xv.x - xv.y, 0.0f), en0 = fmaxf(xv.y - xv.x, 0.0f);
        float pn1 = fmaxf(xv.z - xv.w, 0.0f), en1 = fmaxf(xv.w - xv.z, 0.0f);
        float4 o0 = {(xv.x - mu[0]) * is[0], (xv.y - mu[1]) * is[1],
                     (pn0 - mu[2]) * is[2], (en0 - mu[3]) * is[3]};
        float4 o1 = {(pp0.x - mu[4]) * is[4], (pp0.y - mu[5]) * is[5],
                     (xv.z - mu[0]) * is[0], (xv.w - mu[1]) * is[1]};
        float4 o2 = {(pn1 - mu[2]) * is[2], (en1 - mu[3]) * is[3],
                     (pp1.x - mu[4]) * is[4], (pp1.y - mu[5]) * is[5]};
        *(float4*)(o + 0) = o0;
        *(float4*)(o + 4) = o1;
        *(float4*)(o + 8) = o2;
    }
}

extern "C" void kernel_launch(void* const* d_in, const int* in_sizes, int n_in,
                              void* d_out, int out_size, void* d_ws, size_t ws_size,
                              hipStream_t stream) {
    const float2* x = (const float2*)d_in[0];
    const float* x1 = (const float*)d_in[1];
    float* out = (float*)d_out;
    double* stats = (double*)d_ws;
    float* musig = (float*)((char*)d_ws + 12 * sizeof(double));

    hipMemsetAsync(d_ws, 0, 12 * sizeof(double), stream);
    scan_kernel<<<C_CHUNKS / 64, 64, 0, stream>>>(x, x1, out, stats);
    finalize_stats<<<1, 64, 0, stream>>>(stats, musig);
    normalize_kernel<<<2048, 256, 0, stream>>>((const float4*)x, out, musig);
}